// Round 1
// baseline (1446.142 us; speedup 1.0000x reference)
//
#include <hip/hip_runtime.h>
#include <hip/hip_bf16.h>

#define N_NODE 50000
#define N_EDGE 625000
#define FDIM 128

typedef __bf16 bf16x8 __attribute__((ext_vector_type(8)));
typedef float floatx4 __attribute__((ext_vector_type(4)));

#define MT 64        // nodes per block
#define XS_LD 264    // x-tile row stride (bf16): 256 + 8 pad, 16B-aligned rows, 2-way banks
#define W_LD 40      // staged-W row stride (bf16): 32 + 8 pad, 16B-aligned rows
#define H_LD 136     // h row stride (bf16): 128 + 8 pad, 16B-aligned rows

// -------------------- scatter-add: agg[recv[e]] += edge_feature[e] --------------------
__global__ __launch_bounds__(256) void scatter_kernel(
    const float4* __restrict__ ef, const int* __restrict__ recv,
    float* __restrict__ agg)
{
    long idx = (long)blockIdx.x * 256 + threadIdx.x;   // one float4 of one edge
    const long total = (long)N_EDGE * 32;
    if (idx >= total) return;
    int e = (int)(idx >> 5);
    int c = (int)(idx & 31);
    float4 v = ef[idx];                 // [e][c] since idx = e*32 + c
    int r = recv[e];
    float* dst = agg + (long)r * FDIM + c * 4;
    atomicAdd(dst + 0, v.x);
    atomicAdd(dst + 1, v.y);
    atomicAdd(dst + 2, v.z);
    atomicAdd(dst + 3, v.w);
}

// -------------------- fused MLP + LayerNorm + residual --------------------
__global__ __launch_bounds__(256, 2) void mlp_kernel(
    const float* __restrict__ nodef, const float* __restrict__ agg,
    const float* __restrict__ W1, const float* __restrict__ b1,
    const float* __restrict__ W2, const float* __restrict__ b2,
    const float* __restrict__ W3, const float* __restrict__ b3,
    const float* __restrict__ gamma, const float* __restrict__ beta,
    float* __restrict__ out)
{
    __shared__ __bf16 xs[MT * XS_LD];    // 33792 B: x = [node || agg], bf16
    __shared__ __bf16 wb[128 * W_LD];    // 10240 B: staged W^T chunk [n][k_local]
    __shared__ __bf16 h1[MT * H_LD];     // 17408 B
    __bf16* h2 = xs;                     // reuse xs after GEMM1 (H_LD stride)

    const int t = threadIdx.x;
    const int wave = t >> 6;
    const int lane = t & 63;
    const int quad = lane >> 4;
    const int l16 = lane & 15;
    const int w16 = wave << 4;           // this wave's row base (16 rows/wave)
    const int q8 = quad << 3;
    const int node0 = blockIdx.x * MT;

    // ---- load x-tile: cols 0..127 = node_feature, 128..255 = agg ----
    const float4* nf4 = (const float4*)nodef;
    const float4* ag4 = (const float4*)agg;
#pragma unroll
    for (int i = 0; i < 16; ++i) {
        int it = i * 256 + t;
        int row = it >> 6;
        int c4 = it & 63;
        int node = node0 + row;
        if (node >= N_NODE) node = N_NODE - 1;   // clamp; results discarded later
        float4 v = (c4 < 32) ? nf4[(long)node * 32 + c4]
                             : ag4[(long)node * 32 + (c4 - 32)];
        union { __bf16 b[4]; short4 s; } u;
        u.b[0] = (__bf16)v.x; u.b[1] = (__bf16)v.y;
        u.b[2] = (__bf16)v.z; u.b[3] = (__bf16)v.w;
        *(short4*)&xs[row * XS_LD + c4 * 4] = u.s;
    }

    floatx4 acc[8];
    const floatx4 zero = {0.f, 0.f, 0.f, 0.f};

    // stage a 32-wide K chunk of W[K][128] as W^T into wb[n][kl]
    auto stage_w = [&](const float* __restrict__ Wsrc, int k0) {
#pragma unroll
        for (int p = 0; p < 8; ++p) {
            int kl = p * 4 + ((t >> 7) << 1);    // even kl, thread does kl, kl+1
            int n = t & 127;
            float a0 = Wsrc[(k0 + kl) * 128 + n];
            float a1 = Wsrc[(k0 + kl + 1) * 128 + n];
            union { __bf16 b[2]; int i; } u;
            u.b[0] = (__bf16)a0; u.b[1] = (__bf16)a1;
            *(int*)&wb[n * W_LD + kl] = u.i;
        }
    };

    // A[64 x 32*nk] @ W[32*nk x 128] -> acc (per wave: rows w16..w16+15, all 128 cols)
    auto run_gemm = [&](const __bf16* A, int ldA, const float* __restrict__ Wsrc, int nk) {
#pragma unroll
        for (int nt = 0; nt < 8; ++nt) acc[nt] = zero;
        for (int kc = 0; kc < nk; ++kc) {
            stage_w(Wsrc, kc * 32);
            __syncthreads();
            bf16x8 a = *(const bf16x8*)&A[(w16 + l16) * ldA + kc * 32 + q8];
#pragma unroll
            for (int nt = 0; nt < 8; ++nt) {
                bf16x8 b = *(const bf16x8*)&wb[(nt * 16 + l16) * W_LD + q8];
                acc[nt] = __builtin_amdgcn_mfma_f32_16x16x32_bf16(a, b, acc[nt], 0, 0, 0);
            }
            __syncthreads();
        }
    };

    // bias + relu + bf16 store to H
    auto epilogue_relu = [&](const float* __restrict__ bias, __bf16* H) {
#pragma unroll
        for (int nt = 0; nt < 8; ++nt) {
            int col = nt * 16 + l16;
            float bv = bias[col];
#pragma unroll
            for (int r = 0; r < 4; ++r) {
                float v = acc[nt][r] + bv;
                v = v > 0.f ? v : 0.f;
                H[(w16 + quad * 4 + r) * H_LD + col] = (__bf16)v;
            }
        }
    };

    run_gemm(xs, XS_LD, W1, 8);      // K = 256
    epilogue_relu(b1, h1);
    run_gemm(h1, H_LD, W2, 4);       // K = 128
    epilogue_relu(b2, h2);
    run_gemm(h2, H_LD, W3, 4);       // K = 128

    // ---- final epilogue: +b3, LayerNorm over 128 cols, gamma/beta, +residual ----
    float vout[8][4];
    float sum[4] = {0.f, 0.f, 0.f, 0.f};
    float sq[4]  = {0.f, 0.f, 0.f, 0.f};
#pragma unroll
    for (int nt = 0; nt < 8; ++nt) {
        int col = nt * 16 + l16;
        float bv = b3[col];
#pragma unroll
        for (int r = 0; r < 4; ++r) {
            float v = acc[nt][r] + bv;
            vout[nt][r] = v;
            sum[r] += v;
            sq[r] += v * v;
        }
    }
    // row sums live across the 16 lanes sharing a quad; reduce within that group
#pragma unroll
    for (int r = 0; r < 4; ++r) {
#pragma unroll
        for (int off = 1; off < 16; off <<= 1) {
            sum[r] += __shfl_xor(sum[r], off);
            sq[r]  += __shfl_xor(sq[r], off);
        }
    }
    float mu[4], rs[4];
#pragma unroll
    for (int r = 0; r < 4; ++r) {
        mu[r] = sum[r] * (1.f / 128.f);
        float var = sq[r] * (1.f / 128.f) - mu[r] * mu[r];
        rs[r] = rsqrtf(var + 1e-5f);
    }
#pragma unroll
    for (int nt = 0; nt < 8; ++nt) {
        int col = nt * 16 + l16;
        float g = gamma[col], be = beta[col];
#pragma unroll
        for (int r = 0; r < 4; ++r) {
            int row = w16 + quad * 4 + r;
            int node = node0 + row;
            if (node < N_NODE) {
                long off = (long)node * 128 + col;
                out[off] = (vout[nt][r] - mu[r]) * rs[r] * g + be + nodef[off];
            }
        }
    }
}

extern "C" void kernel_launch(void* const* d_in, const int* in_sizes, int n_in,
                              void* d_out, int out_size, void* d_ws, size_t ws_size,
                              hipStream_t stream)
{
    const float* nodef = (const float*)d_in[0];
    const int*   em    = (const int*)d_in[1];
    const float* ef    = (const float*)d_in[2];
    const float* W1    = (const float*)d_in[3];
    const float* b1    = (const float*)d_in[4];
    const float* W2    = (const float*)d_in[5];
    const float* b2    = (const float*)d_in[6];
    const float* W3    = (const float*)d_in[7];
    const float* b3    = (const float*)d_in[8];
    const float* gamma = (const float*)d_in[9];
    const float* beta  = (const float*)d_in[10];
    float* out = (float*)d_out;
    float* agg = (float*)d_ws;                    // [N_NODE][FDIM] fp32 scratch

    // ws is poisoned 0xAA before every call — zero agg each launch
    hipMemsetAsync(agg, 0, (size_t)N_NODE * FDIM * sizeof(float), stream);

    const int* recv = em + N_EDGE;                // edge_matrix row 1 = receivers
    long total = (long)N_EDGE * 32;               // float4 work items
    int sblocks = (int)((total + 255) / 256);     // = 78125
    scatter_kernel<<<sblocks, 256, 0, stream>>>((const float4*)ef, recv, agg);

    int mblocks = (N_NODE + MT - 1) / MT;         // = 782
    mlp_kernel<<<mblocks, 256, 0, stream>>>(nodef, agg, W1, b1, W2, b2,
                                            W3, b3, gamma, beta, out);
}

// Round 2
// 630.755 us; speedup vs baseline: 2.2927x; 2.2927x over previous
//
#include <hip/hip_runtime.h>
#include <hip/hip_bf16.h>

#define N_NODE 50000
#define N_EDGE 625000
#define FDIM 128
#define NB_SCAN 196   // ceil(50000/256)

typedef __bf16 bf16x8 __attribute__((ext_vector_type(8)));
typedef float floatx4 __attribute__((ext_vector_type(4)));

#define MT 64        // nodes per block
#define XS_LD 264    // x-tile row stride (bf16): 256 + 8 pad
#define W_LD 40      // staged-W row stride (bf16): 32 + 8 pad
#define H_LD 136     // h row stride (bf16): 128 + 8 pad

// ---------------- CSR build ----------------
__global__ __launch_bounds__(256) void hist_kernel(
    const int* __restrict__ recv, int* __restrict__ count, int* __restrict__ pos)
{
    int e = blockIdx.x * 256 + threadIdx.x;
    if (e < N_EDGE) pos[e] = atomicAdd(&count[recv[e]], 1);
}

__global__ __launch_bounds__(256) void scan1_kernel(
    const int* __restrict__ count, int* __restrict__ off, int* __restrict__ bsum)
{
    __shared__ int s[256];
    int t = threadIdx.x;
    int i = blockIdx.x * 256 + t;
    int v = (i < N_NODE) ? count[i] : 0;
    s[t] = v;
    __syncthreads();
    for (int d = 1; d < 256; d <<= 1) {
        int x = (t >= d) ? s[t - d] : 0;
        __syncthreads();
        s[t] += x;
        __syncthreads();
    }
    if (i < N_NODE) off[i] = s[t] - v;              // block-local exclusive
    if (t == 255) bsum[blockIdx.x] = s[255];        // block total
}

__global__ __launch_bounds__(256) void scan2_kernel(int* __restrict__ bsum)
{
    __shared__ int s[256];
    int t = threadIdx.x;
    int v = (t < NB_SCAN) ? bsum[t] : 0;
    s[t] = v;
    __syncthreads();
    for (int d = 1; d < 256; d <<= 1) {
        int x = (t >= d) ? s[t - d] : 0;
        __syncthreads();
        s[t] += x;
        __syncthreads();
    }
    if (t < NB_SCAN) bsum[t] = s[t] - v;            // exclusive block bases
}

__global__ __launch_bounds__(256) void scan3_kernel(
    int* __restrict__ off, const int* __restrict__ bsum)
{
    int i = blockIdx.x * 256 + threadIdx.x;
    if (i < N_NODE) off[i] += bsum[blockIdx.x];
    if (i == N_NODE) off[i] = N_EDGE;               // sentinel: off[50000]
}

__global__ __launch_bounds__(256) void fill_kernel(
    const int* __restrict__ recv, const int* __restrict__ pos,
    const int* __restrict__ off, int* __restrict__ eid)
{
    int e = blockIdx.x * 256 + threadIdx.x;
    if (e < N_EDGE) {
        int r = recv[e];
        eid[off[r] + pos[e]] = e;
    }
}

// ------------- fused gather + MLP + LayerNorm + residual -------------
__global__ __launch_bounds__(256, 2) void mlp_kernel(
    const float* __restrict__ nodef, const float* __restrict__ ef,
    const int* __restrict__ off, const int* __restrict__ eid,
    const float* __restrict__ W1, const float* __restrict__ b1,
    const float* __restrict__ W2, const float* __restrict__ b2,
    const float* __restrict__ W3, const float* __restrict__ b3,
    const float* __restrict__ gamma, const float* __restrict__ beta,
    float* __restrict__ out)
{
    __shared__ __bf16 xs[MT * XS_LD];    // x = [node || gathered agg], bf16
    __shared__ __bf16 wb[128 * W_LD];    // staged W^T chunk [n][k_local]
    __shared__ __bf16 h1[MT * H_LD];
    __bf16* h2 = xs;                     // reuse xs after GEMM1

    const int t = threadIdx.x;
    const int wave = t >> 6;
    const int lane = t & 63;
    const int quad = lane >> 4;
    const int l16 = lane & 15;
    const int w16 = wave << 4;
    const int q8 = quad << 3;
    const int node0 = blockIdx.x * MT;

    // ---- phase 1: node features -> xs cols 0..127 ----
    const float4* nf4 = (const float4*)nodef;
#pragma unroll
    for (int i = 0; i < 8; ++i) {
        int it = i * 256 + t;
        int row = it >> 5;
        int c4 = it & 31;
        int node = node0 + row;
        if (node >= N_NODE) node = N_NODE - 1;   // junk ok; masked at store
        float4 v = nf4[(long)node * 32 + c4];
        union { __bf16 b[4]; short4 s; } u;
        u.b[0] = (__bf16)v.x; u.b[1] = (__bf16)v.y;
        u.b[2] = (__bf16)v.z; u.b[3] = (__bf16)v.w;
        *(short4*)&xs[row * XS_LD + c4 * 4] = u.s;
    }

    // ---- phase 2: CSR gather -> xs cols 128..255 (wave owns rows w16..w16+15) ----
    const float2* ef2 = (const float2*)ef;
    for (int r0 = 0; r0 < 16; ++r0) {
        int row = w16 + r0;
        int node = node0 + row;
        float ax = 0.f, ay = 0.f;
        if (node < N_NODE) {
            int s0 = off[node], e0 = off[node + 1];
            int j = s0;
            for (; j + 4 <= e0; j += 4) {
                int i0 = eid[j], i1 = eid[j + 1], i2 = eid[j + 2], i3 = eid[j + 3];
                float2 v0 = ef2[(long)i0 * 64 + lane];
                float2 v1 = ef2[(long)i1 * 64 + lane];
                float2 v2 = ef2[(long)i2 * 64 + lane];
                float2 v3 = ef2[(long)i3 * 64 + lane];
                ax += v0.x + v1.x + v2.x + v3.x;
                ay += v0.y + v1.y + v2.y + v3.y;
            }
            for (; j < e0; ++j) {
                int i0 = eid[j];
                float2 v0 = ef2[(long)i0 * 64 + lane];
                ax += v0.x; ay += v0.y;
            }
        }
        union { __bf16 b[2]; int iv; } u;
        u.b[0] = (__bf16)ax; u.b[1] = (__bf16)ay;
        *(int*)&xs[row * XS_LD + 128 + lane * 2] = u.iv;
    }

    floatx4 acc[8];
    const floatx4 zero = {0.f, 0.f, 0.f, 0.f};

    auto stage_w = [&](const float* __restrict__ Wsrc, int k0) {
#pragma unroll
        for (int p = 0; p < 8; ++p) {
            int kl = p * 4 + ((t >> 7) << 1);
            int n = t & 127;
            float a0 = Wsrc[(k0 + kl) * 128 + n];
            float a1 = Wsrc[(k0 + kl + 1) * 128 + n];
            union { __bf16 b[2]; int i; } u;
            u.b[0] = (__bf16)a0; u.b[1] = (__bf16)a1;
            *(int*)&wb[n * W_LD + kl] = u.i;
        }
    };

    auto run_gemm = [&](const __bf16* A, int ldA, const float* __restrict__ Wsrc, int nk) {
#pragma unroll
        for (int nt = 0; nt < 8; ++nt) acc[nt] = zero;
        for (int kc = 0; kc < nk; ++kc) {
            stage_w(Wsrc, kc * 32);
            __syncthreads();               // also orders phase1/2 xs writes
            bf16x8 a = *(const bf16x8*)&A[(w16 + l16) * ldA + kc * 32 + q8];
#pragma unroll
            for (int nt = 0; nt < 8; ++nt) {
                bf16x8 b = *(const bf16x8*)&wb[(nt * 16 + l16) * W_LD + q8];
                acc[nt] = __builtin_amdgcn_mfma_f32_16x16x32_bf16(a, b, acc[nt], 0, 0, 0);
            }
            __syncthreads();
        }
    };

    auto epilogue_relu = [&](const float* __restrict__ bias, __bf16* H) {
#pragma unroll
        for (int nt = 0; nt < 8; ++nt) {
            int col = nt * 16 + l16;
            float bv = bias[col];
#pragma unroll
            for (int r = 0; r < 4; ++r) {
                float v = acc[nt][r] + bv;
                v = v > 0.f ? v : 0.f;
                H[(w16 + quad * 4 + r) * H_LD + col] = (__bf16)v;
            }
        }
    };

    run_gemm(xs, XS_LD, W1, 8);      // K = 256
    epilogue_relu(b1, h1);
    run_gemm(h1, H_LD, W2, 4);       // K = 128
    epilogue_relu(b2, h2);
    run_gemm(h2, H_LD, W3, 4);       // K = 128

    // ---- final: +b3, LayerNorm, gamma/beta, +residual ----
    float vout[8][4];
    float sum[4] = {0.f, 0.f, 0.f, 0.f};
    float sq[4]  = {0.f, 0.f, 0.f, 0.f};
#pragma unroll
    for (int nt = 0; nt < 8; ++nt) {
        int col = nt * 16 + l16;
        float bv = b3[col];
#pragma unroll
        for (int r = 0; r < 4; ++r) {
            float v = acc[nt][r] + bv;
            vout[nt][r] = v;
            sum[r] += v;
            sq[r] += v * v;
        }
    }
#pragma unroll
    for (int r = 0; r < 4; ++r) {
#pragma unroll
        for (int offs = 1; offs < 16; offs <<= 1) {
            sum[r] += __shfl_xor(sum[r], offs);
            sq[r]  += __shfl_xor(sq[r], offs);
        }
    }
    float mu[4], rs[4];
#pragma unroll
    for (int r = 0; r < 4; ++r) {
        mu[r] = sum[r] * (1.f / 128.f);
        float var = sq[r] * (1.f / 128.f) - mu[r] * mu[r];
        rs[r] = rsqrtf(var + 1e-5f);
    }
#pragma unroll
    for (int nt = 0; nt < 8; ++nt) {
        int col = nt * 16 + l16;
        float g = gamma[col], be = beta[col];
#pragma unroll
        for (int r = 0; r < 4; ++r) {
            int row = w16 + quad * 4 + r;
            int node = node0 + row;
            if (node < N_NODE) {
                long o = (long)node * 128 + col;
                out[o] = (vout[nt][r] - mu[r]) * rs[r] * g + be + nodef[o];
            }
        }
    }
}

extern "C" void kernel_launch(void* const* d_in, const int* in_sizes, int n_in,
                              void* d_out, int out_size, void* d_ws, size_t ws_size,
                              hipStream_t stream)
{
    const float* nodef = (const float*)d_in[0];
    const int*   em    = (const int*)d_in[1];
    const float* ef    = (const float*)d_in[2];
    const float* W1    = (const float*)d_in[3];
    const float* b1    = (const float*)d_in[4];
    const float* W2    = (const float*)d_in[5];
    const float* b2    = (const float*)d_in[6];
    const float* W3    = (const float*)d_in[7];
    const float* b3    = (const float*)d_in[8];
    const float* gamma = (const float*)d_in[9];
    const float* beta  = (const float*)d_in[10];
    float* out = (float*)d_out;

    // workspace layout (ints)
    int* count = (int*)d_ws;             // 50000  (zeroed below)
    int* pos   = count + 50048;          // 625000
    int* off   = pos + 625024;           // 50001 (+ sentinel)
    int* bsum  = off + 50048;            // 196
    int* eid   = bsum + 256;             // 625000

    const int* recv = em + N_EDGE;       // edge_matrix row 1 = receivers

    hipMemsetAsync(count, 0, (size_t)N_NODE * sizeof(int), stream);

    int eblocks = (N_EDGE + 255) / 256;  // 2442
    hist_kernel<<<eblocks, 256, 0, stream>>>(recv, count, pos);
    scan1_kernel<<<NB_SCAN, 256, 0, stream>>>(count, off, bsum);
    scan2_kernel<<<1, 256, 0, stream>>>(bsum);
    scan3_kernel<<<NB_SCAN, 256, 0, stream>>>(off, bsum);
    fill_kernel<<<eblocks, 256, 0, stream>>>(recv, pos, off, eid);

    int mblocks = (N_NODE + MT - 1) / MT;   // 782
    mlp_kernel<<<mblocks, 256, 0, stream>>>(nodef, ef, off, eid,
                                            W1, b1, W2, b2, W3, b3,
                                            gamma, beta, out);
}

// Round 3
// 553.553 us; speedup vs baseline: 2.6125x; 1.1395x over previous
//
#include <hip/hip_runtime.h>
#include <hip/hip_bf16.h>

#define N_NODE 50000
#define N_EDGE 625000
#define FDIM 128
#define NB_SCAN 196   // ceil(50000/256)

typedef __bf16 bf16x8 __attribute__((ext_vector_type(8)));
typedef float floatx4 __attribute__((ext_vector_type(4)));

#define MT 64        // nodes per block
#define XS_LD 264    // x-tile row stride (bf16): 256 + 8 pad (row = 528 B = 33*16, 16B-aligned)
#define W_LD 40      // staged-W row stride (bf16): 32 + 8 pad
#define H_LD 136     // h row stride (bf16): 128 + 8 pad

// ---------------- CSR build ----------------
__global__ __launch_bounds__(256) void hist_kernel(
    const int* __restrict__ recv, int* __restrict__ count, int* __restrict__ pos)
{
    int e = blockIdx.x * 256 + threadIdx.x;
    if (e < N_EDGE) pos[e] = atomicAdd(&count[recv[e]], 1);
}

__global__ __launch_bounds__(256) void scan1_kernel(
    const int* __restrict__ count, int* __restrict__ off, int* __restrict__ bsum)
{
    __shared__ int s[256];
    int t = threadIdx.x;
    int i = blockIdx.x * 256 + t;
    int v = (i < N_NODE) ? count[i] : 0;
    s[t] = v;
    __syncthreads();
    for (int d = 1; d < 256; d <<= 1) {
        int x = (t >= d) ? s[t - d] : 0;
        __syncthreads();
        s[t] += x;
        __syncthreads();
    }
    if (i < N_NODE) off[i] = s[t] - v;              // block-local exclusive
    if (t == 255) bsum[blockIdx.x] = s[255];        // block total
}

// scan the 196 block sums redundantly per block, then add base
__global__ __launch_bounds__(256) void scan2_kernel(
    int* __restrict__ off, const int* __restrict__ bsum)
{
    __shared__ int s[256];
    int t = threadIdx.x;
    int v = (t < NB_SCAN) ? bsum[t] : 0;
    s[t] = v;
    __syncthreads();
    for (int d = 1; d < 256; d <<= 1) {
        int x = (t >= d) ? s[t - d] : 0;
        __syncthreads();
        s[t] += x;
        __syncthreads();
    }
    // s[t] = inclusive sum; base for block b = s[b] - bsum[b]
    int i = blockIdx.x * 256 + t;
    if (i < N_NODE) off[i] += s[blockIdx.x] - ((blockIdx.x < NB_SCAN) ? bsum[blockIdx.x] : 0);
    if (i == N_NODE) off[i] = N_EDGE;               // sentinel
}

__global__ __launch_bounds__(256) void fill_kernel(
    const int* __restrict__ recv, const int* __restrict__ pos,
    const int* __restrict__ off, int* __restrict__ eid)
{
    int e = blockIdx.x * 256 + threadIdx.x;
    if (e < N_EDGE) {
        int r = recv[e];
        eid[off[r] + pos[e]] = e;
    }
}

// ---------------- edge gather: one wave per node ----------------
__global__ __launch_bounds__(256) void gather_kernel(
    const float2* __restrict__ ef2, const int* __restrict__ off,
    const int* __restrict__ eid, int* __restrict__ agg32)
{
    int wave = threadIdx.x >> 6;
    int lane = threadIdx.x & 63;
    int node = blockIdx.x * 4 + wave;                // grid = 12500, exact
    float ax = 0.f, ay = 0.f;
    int s0 = off[node], e0 = off[node + 1];
    for (int base = s0; base < e0; base += 64) {
        int cnt = e0 - base; if (cnt > 64) cnt = 64;
        int my_e = (lane < cnt) ? eid[base + lane] : 0;   // 1 coalesced load = up to 64 ids
        int j = 0;
        for (; j + 4 <= cnt; j += 4) {
            int ea = __shfl(my_e, j);
            int eb = __shfl(my_e, j + 1);
            int ec = __shfl(my_e, j + 2);
            int ed = __shfl(my_e, j + 3);
            float2 va = ef2[(long)ea * 64 + lane];
            float2 vb = ef2[(long)eb * 64 + lane];
            float2 vc = ef2[(long)ec * 64 + lane];
            float2 vd = ef2[(long)ed * 64 + lane];
            ax += va.x + vb.x + vc.x + vd.x;
            ay += va.y + vb.y + vc.y + vd.y;
        }
        for (; j < cnt; ++j) {
            int e = __shfl(my_e, j);
            float2 v = ef2[(long)e * 64 + lane];
            ax += v.x; ay += v.y;
        }
    }
    union { __bf16 b[2]; int iv; } u;
    u.b[0] = (__bf16)ax; u.b[1] = (__bf16)ay;
    agg32[(long)node * 64 + lane] = u.iv;            // bf16 agg row, coalesced 256 B
}

// ------------- MLP + LayerNorm + residual (GEMM only) -------------
__global__ __launch_bounds__(256, 2) void mlp_kernel(
    const float* __restrict__ nodef, const int* __restrict__ agg32,
    const float* __restrict__ W1, const float* __restrict__ b1,
    const float* __restrict__ W2, const float* __restrict__ b2,
    const float* __restrict__ W3, const float* __restrict__ b3,
    const float* __restrict__ gamma, const float* __restrict__ beta,
    float* __restrict__ out)
{
    __shared__ __bf16 xs[MT * XS_LD];    // x = [node || agg], bf16
    __shared__ __bf16 wb[128 * W_LD];    // staged W^T chunk [n][k_local]
    __shared__ __bf16 h1[MT * H_LD];
    __bf16* h2 = xs;                     // reuse xs after GEMM1

    const int t = threadIdx.x;
    const int wave = t >> 6;
    const int lane = t & 63;
    const int quad = lane >> 4;
    const int l16 = lane & 15;
    const int w16 = wave << 4;
    const int q8 = quad << 3;
    const int node0 = blockIdx.x * MT;

    // ---- stage x-tile: cols 0..127 node features (fp32->bf16), 128..255 agg (bf16 copy) ----
    const float4* nf4 = (const float4*)nodef;
#pragma unroll
    for (int i = 0; i < 8; ++i) {
        int it = i * 256 + t;
        int row = it >> 5;
        int c4 = it & 31;
        int node = node0 + row;
        if (node >= N_NODE) node = N_NODE - 1;   // junk ok; masked at store
        float4 v = nf4[(long)node * 32 + c4];
        union { __bf16 b[4]; short4 s; } u;
        u.b[0] = (__bf16)v.x; u.b[1] = (__bf16)v.y;
        u.b[2] = (__bf16)v.z; u.b[3] = (__bf16)v.w;
        *(short4*)&xs[row * XS_LD + c4 * 4] = u.s;
    }
    const int4* ag4 = (const int4*)agg32;        // 8 bf16 per int4; 16 int4 per row
#pragma unroll
    for (int i = 0; i < 4; ++i) {
        int it = i * 256 + t;
        int row = it >> 4;
        int c8 = it & 15;
        int node = node0 + row;
        if (node >= N_NODE) node = N_NODE - 1;
        int4 v = ag4[(long)node * 16 + c8];
        *(int4*)&xs[row * XS_LD + 128 + c8 * 8] = v;
    }

    floatx4 acc[8];
    const floatx4 zero = {0.f, 0.f, 0.f, 0.f};

    auto stage_w = [&](const float* __restrict__ Wsrc, int k0) {
#pragma unroll
        for (int p = 0; p < 8; ++p) {
            int kl = p * 4 + ((t >> 7) << 1);
            int n = t & 127;
            float a0 = Wsrc[(k0 + kl) * 128 + n];
            float a1 = Wsrc[(k0 + kl + 1) * 128 + n];
            union { __bf16 b[2]; int i; } u;
            u.b[0] = (__bf16)a0; u.b[1] = (__bf16)a1;
            *(int*)&wb[n * W_LD + kl] = u.i;
        }
    };

    auto run_gemm = [&](const __bf16* A, int ldA, const float* __restrict__ Wsrc, int nk) {
#pragma unroll
        for (int nt = 0; nt < 8; ++nt) acc[nt] = zero;
        for (int kc = 0; kc < nk; ++kc) {
            stage_w(Wsrc, kc * 32);
            __syncthreads();               // also orders x-tile staging
            bf16x8 a = *(const bf16x8*)&A[(w16 + l16) * ldA + kc * 32 + q8];
#pragma unroll
            for (int nt = 0; nt < 8; ++nt) {
                bf16x8 b = *(const bf16x8*)&wb[(nt * 16 + l16) * W_LD + q8];
                acc[nt] = __builtin_amdgcn_mfma_f32_16x16x32_bf16(a, b, acc[nt], 0, 0, 0);
            }
            __syncthreads();
        }
    };

    auto epilogue_relu = [&](const float* __restrict__ bias, __bf16* H) {
#pragma unroll
        for (int nt = 0; nt < 8; ++nt) {
            int col = nt * 16 + l16;
            float bv = bias[col];
#pragma unroll
            for (int r = 0; r < 4; ++r) {
                float v = acc[nt][r] + bv;
                v = v > 0.f ? v : 0.f;
                H[(w16 + quad * 4 + r) * H_LD + col] = (__bf16)v;
            }
        }
    };

    run_gemm(xs, XS_LD, W1, 8);      // K = 256
    epilogue_relu(b1, h1);
    run_gemm(h1, H_LD, W2, 4);       // K = 128
    epilogue_relu(b2, h2);
    run_gemm(h2, H_LD, W3, 4);       // K = 128

    // ---- final: +b3, LayerNorm, gamma/beta, +residual ----
    float vout[8][4];
    float sum[4] = {0.f, 0.f, 0.f, 0.f};
    float sq[4]  = {0.f, 0.f, 0.f, 0.f};
#pragma unroll
    for (int nt = 0; nt < 8; ++nt) {
        int col = nt * 16 + l16;
        float bv = b3[col];
#pragma unroll
        for (int r = 0; r < 4; ++r) {
            float v = acc[nt][r] + bv;
            vout[nt][r] = v;
            sum[r] += v;
            sq[r] += v * v;
        }
    }
#pragma unroll
    for (int r = 0; r < 4; ++r) {
#pragma unroll
        for (int offs = 1; offs < 16; offs <<= 1) {
            sum[r] += __shfl_xor(sum[r], offs);
            sq[r]  += __shfl_xor(sq[r], offs);
        }
    }
    float mu[4], rs[4];
#pragma unroll
    for (int r = 0; r < 4; ++r) {
        mu[r] = sum[r] * (1.f / 128.f);
        float var = sq[r] * (1.f / 128.f) - mu[r] * mu[r];
        rs[r] = rsqrtf(var + 1e-5f);
    }
#pragma unroll
    for (int nt = 0; nt < 8; ++nt) {
        int col = nt * 16 + l16;
        float g = gamma[col], be = beta[col];
#pragma unroll
        for (int r = 0; r < 4; ++r) {
            int row = w16 + quad * 4 + r;
            int node = node0 + row;
            if (node < N_NODE) {
                long o = (long)node * 128 + col;
                out[o] = (vout[nt][r] - mu[r]) * rs[r] * g + be + nodef[o];
            }
        }
    }
}

extern "C" void kernel_launch(void* const* d_in, const int* in_sizes, int n_in,
                              void* d_out, int out_size, void* d_ws, size_t ws_size,
                              hipStream_t stream)
{
    const float* nodef = (const float*)d_in[0];
    const int*   em    = (const int*)d_in[1];
    const float* ef    = (const float*)d_in[2];
    const float* W1    = (const float*)d_in[3];
    const float* b1    = (const float*)d_in[4];
    const float* W2    = (const float*)d_in[5];
    const float* b2    = (const float*)d_in[6];
    const float* W3    = (const float*)d_in[7];
    const float* b3    = (const float*)d_in[8];
    const float* gamma = (const float*)d_in[9];
    const float* beta  = (const float*)d_in[10];
    float* out = (float*)d_out;

    // workspace layout (ints)
    int* count = (int*)d_ws;             // 50048
    int* pos   = count + 50048;          // 625024
    int* off   = pos + 625024;           // 50048 (incl sentinel)
    int* bsum  = off + 50048;            // 256
    int* eid   = bsum + 256;             // 625024
    int* agg32 = eid + 625024;           // 50000*64 ints (bf16x2) = 12.8 MB

    const int* recv = em + N_EDGE;       // edge_matrix row 1 = receivers

    hipMemsetAsync(count, 0, (size_t)N_NODE * sizeof(int), stream);

    int eblocks = (N_EDGE + 255) / 256;  // 2442
    hist_kernel<<<eblocks, 256, 0, stream>>>(recv, count, pos);
    scan1_kernel<<<NB_SCAN, 256, 0, stream>>>(count, off, bsum);
    scan2_kernel<<<NB_SCAN, 256, 0, stream>>>(off, bsum);
    fill_kernel<<<eblocks, 256, 0, stream>>>(recv, pos, off, eid);
    gather_kernel<<<N_NODE / 4, 256, 0, stream>>>((const float2*)ef, off, eid, agg32);

    int mblocks = (N_NODE + MT - 1) / MT;   // 782
    mlp_kernel<<<mblocks, 256, 0, stream>>>(nodef, agg32, W1, b1, W2, b2,
                                            W3, b3, gamma, beta, out);
}

// Round 4
// 548.011 us; speedup vs baseline: 2.6389x; 1.0101x over previous
//
#include <hip/hip_runtime.h>
#include <hip/hip_bf16.h>

#define N_NODE 50000
#define N_EDGE 625000
#define FDIM 128
#define NB_SCAN 196   // ceil(50000/256)

typedef __bf16 bf16x8 __attribute__((ext_vector_type(8)));
typedef float floatx4 __attribute__((ext_vector_type(4)));

#define MT 64        // nodes per block
#define XS_LD 264    // x-tile row stride (bf16): 256 + 8 pad (row = 528 B, 16B-aligned)
#define H_LD 136     // h row stride (bf16): 128 + 8 pad

__device__ inline bf16x8 as_bf16x8(uint4 v) {
    union { uint4 u; bf16x8 b; } c; c.u = v; return c.b;
}

// ---------------- CSR build ----------------
__global__ __launch_bounds__(256) void hist_kernel(
    const int* __restrict__ recv, int* __restrict__ count, int* __restrict__ pos)
{
    int e = blockIdx.x * 256 + threadIdx.x;
    if (e < N_EDGE) pos[e] = atomicAdd(&count[recv[e]], 1);
}

__global__ __launch_bounds__(256) void scan1_kernel(
    const int* __restrict__ count, int* __restrict__ off, int* __restrict__ bsum)
{
    __shared__ int s[256];
    int t = threadIdx.x;
    int i = blockIdx.x * 256 + t;
    int v = (i < N_NODE) ? count[i] : 0;
    s[t] = v;
    __syncthreads();
    for (int d = 1; d < 256; d <<= 1) {
        int x = (t >= d) ? s[t - d] : 0;
        __syncthreads();
        s[t] += x;
        __syncthreads();
    }
    if (i < N_NODE) off[i] = s[t] - v;              // block-local exclusive
    if (t == 255) bsum[blockIdx.x] = s[255];        // block total
}

// scan the 196 block sums redundantly per block, then add base
__global__ __launch_bounds__(256) void scan2_kernel(
    int* __restrict__ off, const int* __restrict__ bsum)
{
    __shared__ int s[256];
    int t = threadIdx.x;
    int v = (t < NB_SCAN) ? bsum[t] : 0;
    s[t] = v;
    __syncthreads();
    for (int d = 1; d < 256; d <<= 1) {
        int x = (t >= d) ? s[t - d] : 0;
        __syncthreads();
        s[t] += x;
        __syncthreads();
    }
    int i = blockIdx.x * 256 + t;
    if (i < N_NODE) off[i] += s[blockIdx.x] - ((blockIdx.x < NB_SCAN) ? bsum[blockIdx.x] : 0);
    if (i == N_NODE) off[i] = N_EDGE;               // sentinel
}

__global__ __launch_bounds__(256) void fill_kernel(
    const int* __restrict__ recv, const int* __restrict__ pos,
    const int* __restrict__ off, int* __restrict__ eid)
{
    int e = blockIdx.x * 256 + threadIdx.x;
    if (e < N_EDGE) {
        int r = recv[e];
        eid[off[r] + pos[e]] = e;
    }
}

// ---------------- W repack: fp32 [K][128] -> bf16 MFMA B-fragment order ----------------
// Wpack[tile][nt][lane] = uint4 of 8 bf16: W[k0 + (lane>>4)*8 + j][nt*16 + (lane&15)]
// tiles: 0..7 = W1 (K=256), 8..11 = W2, 12..15 = W3
__global__ __launch_bounds__(256) void wrepack_kernel(
    const float* __restrict__ W1, const float* __restrict__ W2,
    const float* __restrict__ W3, uint4* __restrict__ wp)
{
    int g = blockIdx.x * 256 + threadIdx.x;   // 0..8191
    int lane = g & 63;
    int nt = (g >> 6) & 7;
    int tile = g >> 9;
    const float* W; int k0;
    if (tile < 8)       { W = W1; k0 = tile * 32; }
    else if (tile < 12) { W = W2; k0 = (tile - 8) * 32; }
    else                { W = W3; k0 = (tile - 12) * 32; }
    int n = nt * 16 + (lane & 15);
    int kb = k0 + (lane >> 4) * 8;
    union { __bf16 b[8]; uint4 u; } p;
#pragma unroll
    for (int j = 0; j < 8; ++j) p.b[j] = (__bf16)W[(kb + j) * 128 + n];
    wp[g] = p.u;
}

// ---------------- edge gather: one wave per node, 2 edges per pass ----------------
__global__ __launch_bounds__(256) void gather_kernel(
    const float4* __restrict__ ef4, const int* __restrict__ off,
    const int* __restrict__ eid, uint2* __restrict__ agg)
{
    int wave = threadIdx.x >> 6;
    int lane = threadIdx.x & 63;
    int node = blockIdx.x * 4 + wave;                // grid = 12500, exact
    int half = lane >> 5;                            // which edge of the pair
    int c = lane & 31;                               // float4 column
    float4 acc = {0.f, 0.f, 0.f, 0.f};
    int s0 = off[node], e0 = off[node + 1];
    for (int base = s0; base < e0; base += 64) {
        int cnt = e0 - base; if (cnt > 64) cnt = 64;
        int ids = (lane < cnt) ? eid[base + lane] : 0;   // 1 coalesced load, 64 ids
        int j = 0;
        for (; j + 8 <= cnt; j += 8) {                   // 8 edges: 4 indep 16B loads/lane
            int ea = __shfl(ids, j + half);
            int eb = __shfl(ids, j + 2 + half);
            int ec = __shfl(ids, j + 4 + half);
            int ed = __shfl(ids, j + 6 + half);
            float4 va = ef4[(long)ea * 32 + c];
            float4 vb = ef4[(long)eb * 32 + c];
            float4 vc = ef4[(long)ec * 32 + c];
            float4 vd = ef4[(long)ed * 32 + c];
            acc.x += va.x + vb.x + vc.x + vd.x;
            acc.y += va.y + vb.y + vc.y + vd.y;
            acc.z += va.z + vb.z + vc.z + vd.z;
            acc.w += va.w + vb.w + vc.w + vd.w;
        }
        for (; j < cnt; j += 2) {
            if (j + half < cnt) {
                int e = __shfl(ids, j + half);
                float4 v = ef4[(long)e * 32 + c];
                acc.x += v.x; acc.y += v.y; acc.z += v.z; acc.w += v.w;
            }
        }
    }
    // fold the two halves: lanes 0..31 get cols 4c..4c+3 complete
    acc.x += __shfl_xor(acc.x, 32);
    acc.y += __shfl_xor(acc.y, 32);
    acc.z += __shfl_xor(acc.z, 32);
    acc.w += __shfl_xor(acc.w, 32);
    if (half == 0) {
        union { __bf16 b[4]; uint2 u; } p;
        p.b[0] = (__bf16)acc.x; p.b[1] = (__bf16)acc.y;
        p.b[2] = (__bf16)acc.z; p.b[3] = (__bf16)acc.w;
        agg[(long)node * 32 + c] = p.u;              // 256 B coalesced row
    }
}

// ------------- MLP + LayerNorm + residual -------------
__global__ __launch_bounds__(256, 3) void mlp_kernel(
    const float* __restrict__ nodef, const int* __restrict__ agg32,
    const uint4* __restrict__ wp,
    const float* __restrict__ b1, const float* __restrict__ b2,
    const float* __restrict__ b3,
    const float* __restrict__ gamma, const float* __restrict__ beta,
    float* __restrict__ out)
{
    __shared__ __bf16 xs[MT * XS_LD];    // x = [node || agg], bf16 (33792 B)
    __shared__ __bf16 h1[MT * H_LD];     // 17408 B
    __bf16* h2 = xs;                     // reuse xs after GEMM1

    const int t = threadIdx.x;
    const int wave = t >> 6;
    const int lane = t & 63;
    const int quad = lane >> 4;
    const int l16 = lane & 15;
    const int w16 = wave << 4;
    const int q8 = quad << 3;
    const int node0 = blockIdx.x * MT;

    // ---- stage x-tile ----
    const float4* nf4 = (const float4*)nodef;
#pragma unroll
    for (int i = 0; i < 8; ++i) {
        int it = i * 256 + t;
        int row = it >> 5;
        int c4 = it & 31;
        int node = node0 + row;
        if (node >= N_NODE) node = N_NODE - 1;   // junk ok; masked at store
        float4 v = nf4[(long)node * 32 + c4];
        union { __bf16 b[4]; short4 s; } u;
        u.b[0] = (__bf16)v.x; u.b[1] = (__bf16)v.y;
        u.b[2] = (__bf16)v.z; u.b[3] = (__bf16)v.w;
        *(short4*)&xs[row * XS_LD + c4 * 4] = u.s;
    }
    const int4* ag4 = (const int4*)agg32;        // 16 int4 per agg row
#pragma unroll
    for (int i = 0; i < 4; ++i) {
        int it = i * 256 + t;
        int row = it >> 4;
        int c8 = it & 15;
        int node = node0 + row;
        if (node >= N_NODE) node = N_NODE - 1;
        int4 v = ag4[(long)node * 16 + c8];
        *(int4*)&xs[row * XS_LD + 128 + c8 * 8] = v;
    }

    floatx4 acc[8];
    const floatx4 zero = {0.f, 0.f, 0.f, 0.f};

    // A[64 x 32*nk] @ Wpack-tiles -> acc; B-frags straight from global (L1/L2)
    auto run_gemm = [&](const __bf16* A, int ldA, const uint4* __restrict__ wpt, int nk) {
#pragma unroll
        for (int nt = 0; nt < 8; ++nt) acc[nt] = zero;
        const __bf16* arow = A + (w16 + l16) * ldA + q8;
        bf16x8 a = *(const bf16x8*)arow;
        bf16x8 b[8];
#pragma unroll
        for (int nt = 0; nt < 8; ++nt) b[nt] = as_bf16x8(wpt[nt * 64 + lane]);
        for (int kc = 0; kc < nk; ++kc) {
            bf16x8 a2; bf16x8 b2[8];
            if (kc + 1 < nk) {
                a2 = *(const bf16x8*)(arow + (kc + 1) * 32);
#pragma unroll
                for (int nt = 0; nt < 8; ++nt)
                    b2[nt] = as_bf16x8(wpt[((kc + 1) * 8 + nt) * 64 + lane]);
            }
#pragma unroll
            for (int nt = 0; nt < 8; ++nt)
                acc[nt] = __builtin_amdgcn_mfma_f32_16x16x32_bf16(a, b[nt], acc[nt], 0, 0, 0);
            a = a2;
#pragma unroll
            for (int nt = 0; nt < 8; ++nt) b[nt] = b2[nt];
        }
    };

    auto epilogue_relu = [&](const float* __restrict__ bias, __bf16* H) {
#pragma unroll
        for (int nt = 0; nt < 8; ++nt) {
            int col = nt * 16 + l16;
            float bv = bias[col];
#pragma unroll
            for (int r = 0; r < 4; ++r) {
                float v = acc[nt][r] + bv;
                v = v > 0.f ? v : 0.f;
                H[(w16 + quad * 4 + r) * H_LD + col] = (__bf16)v;
            }
        }
    };

    __syncthreads();                         // xs staged
    run_gemm(xs, XS_LD, wp, 8);              // GEMM1: K = 256
    epilogue_relu(b1, h1);
    __syncthreads();                         // h1 visible; xs reads done
    run_gemm(h1, H_LD, wp + 8 * 8 * 64, 4);  // GEMM2: K = 128
    epilogue_relu(b2, h2);                   // h2 = xs (safe: all waves past GEMM1)
    __syncthreads();                         // h2 visible
    run_gemm(h2, H_LD, wp + 12 * 8 * 64, 4); // GEMM3: K = 128

    // ---- final: +b3, LayerNorm, gamma/beta, +residual ----
    float vout[8][4];
    float sum[4] = {0.f, 0.f, 0.f, 0.f};
    float sq[4]  = {0.f, 0.f, 0.f, 0.f};
#pragma unroll
    for (int nt = 0; nt < 8; ++nt) {
        int col = nt * 16 + l16;
        float bv = b3[col];
#pragma unroll
        for (int r = 0; r < 4; ++r) {
            float v = acc[nt][r] + bv;
            vout[nt][r] = v;
            sum[r] += v;
            sq[r] += v * v;
        }
    }
#pragma unroll
    for (int r = 0; r < 4; ++r) {
#pragma unroll
        for (int offs = 1; offs < 16; offs <<= 1) {
            sum[r] += __shfl_xor(sum[r], offs);
            sq[r]  += __shfl_xor(sq[r], offs);
        }
    }
    float mu[4], rs[4];
#pragma unroll
    for (int r = 0; r < 4; ++r) {
        mu[r] = sum[r] * (1.f / 128.f);
        float var = sq[r] * (1.f / 128.f) - mu[r] * mu[r];
        rs[r] = rsqrtf(var + 1e-5f);
    }
#pragma unroll
    for (int nt = 0; nt < 8; ++nt) {
        int col = nt * 16 + l16;
        float g = gamma[col], be = beta[col];
#pragma unroll
        for (int r = 0; r < 4; ++r) {
            int row = w16 + quad * 4 + r;
            int node = node0 + row;
            if (node < N_NODE) {
                long o = (long)node * 128 + col;
                out[o] = (vout[nt][r] - mu[r]) * rs[r] * g + be + nodef[o];
            }
        }
    }
}

extern "C" void kernel_launch(void* const* d_in, const int* in_sizes, int n_in,
                              void* d_out, int out_size, void* d_ws, size_t ws_size,
                              hipStream_t stream)
{
    const float* nodef = (const float*)d_in[0];
    const int*   em    = (const int*)d_in[1];
    const float* ef    = (const float*)d_in[2];
    const float* W1    = (const float*)d_in[3];
    const float* b1    = (const float*)d_in[4];
    const float* W2    = (const float*)d_in[5];
    const float* b2    = (const float*)d_in[6];
    const float* W3    = (const float*)d_in[7];
    const float* b3    = (const float*)d_in[8];
    const float* gamma = (const float*)d_in[9];
    const float* beta  = (const float*)d_in[10];
    float* out = (float*)d_out;

    // workspace layout (ints)
    int* count = (int*)d_ws;             // 50048
    int* pos   = count + 50048;          // 625024
    int* off   = pos + 625024;           // 50048 (incl sentinel)
    int* bsum  = off + 50048;            // 256
    int* eid   = bsum + 256;             // 625024
    int* agg32 = eid + 625024;           // 50000*64 ints (bf16x2) = 12.8 MB
    uint4* wp  = (uint4*)(agg32 + 3200000);  // 8192 uint4 = 128 KB (16B-aligned: offset mult of 16)

    const int* recv = em + N_EDGE;       // edge_matrix row 1 = receivers

    hipMemsetAsync(count, 0, (size_t)N_NODE * sizeof(int), stream);

    wrepack_kernel<<<32, 256, 0, stream>>>(W1, W2, W3, wp);

    int eblocks = (N_EDGE + 255) / 256;  // 2442
    hist_kernel<<<eblocks, 256, 0, stream>>>(recv, count, pos);
    scan1_kernel<<<NB_SCAN, 256, 0, stream>>>(count, off, bsum);
    scan2_kernel<<<NB_SCAN, 256, 0, stream>>>(off, bsum);
    fill_kernel<<<eblocks, 256, 0, stream>>>(recv, pos, off, eid);
    gather_kernel<<<N_NODE / 4, 256, 0, stream>>>((const float4*)ef, off, eid, (uint2*)agg32);

    int mblocks = (N_NODE + MT - 1) / MT;   // 782
    mlp_kernel<<<mblocks, 256, 0, stream>>>(nodef, agg32, wp, b1, b2, b3,
                                            gamma, beta, out);
}